// Round 1
// baseline (973.848 us; speedup 1.0000x reference)
//
#include <hip/hip_runtime.h>
#include <math.h>

namespace {

constexpr int DD   = 4;    // feature dims
constexpr int NFRQ = 64;   // fourier freqs
constexpr int HH   = 128;  // hidden
constexpr int FF   = 129;  // 2*NFRQ + 1
constexpr int EPB  = 64;   // edges per block
constexpr int EPW  = 16;   // edges per wave
constexpr int XST  = 132;  // LDS row stride (floats), 16B-aligned rows

constexpr float PI_F     = 3.14159265358979323846f;
constexpr float TWO_PI_F = 6.28318530717958647692f;

__global__ __launch_bounds__(256, 4)
void rcpe_fused(const float* __restrict__ source,
                const float* __restrict__ target,
                const int*   __restrict__ edge,
                const float* __restrict__ freqs,
                const float* __restrict__ W1,
                const float* __restrict__ b1,
                const float* __restrict__ gamma,
                const float* __restrict__ beta,
                const float* __restrict__ W2,
                const float* __restrict__ b2,
                float* __restrict__ out,
                int E)
{
    __shared__ float feat_lds[EPB][DD];
    __shared__ float freq_lds[DD][NFRQ];
    __shared__ float xbuf[4][EPW][XST];   // per-wave x tile, reused as h tile

    const int tid  = threadIdx.x;
    const int wave = tid >> 6;
    const int lane = tid & 63;
    const int ebase = blockIdx.x * EPB;

    // stage freqs (4x64 = 256 = blockDim)
    freq_lds[tid >> 6][tid & 63] = freqs[tid];

    // Phase 0: features for this block's 64 edges (one thread each)
    if (tid < EPB) {
        const int e   = ebase + tid;
        const int s_i = edge[e];
        const int t_i = edge[E + e];
        const float sx = source[s_i * 3 + 0];
        const float sy = source[s_i * 3 + 1];
        const float sh = source[s_i * 3 + 2];
        const float tx = target[t_i * 5 + 0];
        const float ty = target[t_i * 5 + 1];
        const float th = target[t_i * 5 + 2];
        const float ts = target[t_i * 5 + 3];
        const float dx = sx - tx;
        const float dy = sy - ty;
        float a = sh - th + PI_F;
        a = fmodf(a, TWO_PI_F);
        if (a < 0.0f) a += TWO_PI_F;
        const float dh  = a - PI_F;
        const float ang = atan2f(dy, dx);
        const float tvx = ts * cosf(th);
        const float tvy = ts * sinf(th);
        const float closing = tvx * cosf(ang) + tvy * sinf(ang);
        feat_lds[tid][0] = dx;
        feat_lds[tid][1] = dy;
        feat_lds[tid][2] = dh;
        feat_lds[tid][3] = closing;
    }
    __syncthreads();

    // persistent accumulators: y[e][lane], y[e][lane+64]; init with sum_d b2
    float y0[EPW], y1[EPW];
    {
        float s0 = 0.0f, s1 = 0.0f;
        #pragma unroll
        for (int d = 0; d < DD; ++d) {
            s0 += b2[d * HH + lane];
            s1 += b2[d * HH + lane + 64];
        }
        #pragma unroll
        for (int e = 0; e < EPW; ++e) { y0[e] = s0; y1[e] = s1; }
    }

    const int eloc = wave * EPW;
    float (*xw)[XST] = xbuf[wave];

    for (int d = 0; d < DD; ++d) {
        // ---- Phase A: build x tile [16 edges][128 fourier feats] in LDS ----
        {
            const int ge = lane >> 2;   // edge 0..15
            const int g  = lane & 3;
            const float fe = feat_lds[eloc + ge][d];
            #pragma unroll
            for (int k = 0; k < 16; ++k) {
                const int nf = g + 4 * k;
                const float fr = freq_lds[d][nf];
                float s, c;
                __sincosf(fe * fr * TWO_PI_F, &s, &c);
                xw[ge][nf] = c;
                xw[ge][NFRQ + nf] = s;
            }
        }
        __syncthreads();

        // ---- Phase B: h = x @ W1[d] + b1[d] (lane owns cols lane, lane+64) ----
        float a0[EPW], a1[EPW];
        {
            const float bb0 = b1[d * HH + lane];
            const float bb1 = b1[d * HH + lane + 64];
            #pragma unroll
            for (int e = 0; e < EPW; ++e) { a0[e] = bb0; a1[e] = bb1; }
        }
        const float* W1d = W1 + d * FF * HH;
        for (int f4 = 0; f4 < 32; ++f4) {
            float w0[4], w1[4];
            #pragma unroll
            for (int j = 0; j < 4; ++j) {
                w0[j] = W1d[(f4 * 4 + j) * HH + lane];
                w1[j] = W1d[(f4 * 4 + j) * HH + lane + 64];
            }
            #pragma unroll
            for (int e = 0; e < EPW; ++e) {
                const float4 xv = *(const float4*)&xw[e][f4 * 4];
                a0[e] = fmaf(xv.x, w0[0], a0[e]);
                a0[e] = fmaf(xv.y, w0[1], a0[e]);
                a0[e] = fmaf(xv.z, w0[2], a0[e]);
                a0[e] = fmaf(xv.w, w0[3], a0[e]);
                a1[e] = fmaf(xv.x, w1[0], a1[e]);
                a1[e] = fmaf(xv.y, w1[1], a1[e]);
                a1[e] = fmaf(xv.z, w1[2], a1[e]);
                a1[e] = fmaf(xv.w, w1[3], a1[e]);
            }
        }
        {   // f = 128 term: raw feature
            const float wl0 = W1d[128 * HH + lane];
            const float wl1 = W1d[128 * HH + lane + 64];
            #pragma unroll
            for (int e = 0; e < EPW; ++e) {
                const float fe = feat_lds[eloc + e][d];
                a0[e] = fmaf(fe, wl0, a0[e]);
                a1[e] = fmaf(fe, wl1, a1[e]);
            }
        }

        // ---- Phase C: LayerNorm + ReLU ----
        {
            const float g0  = gamma[d * HH + lane];
            const float g1  = gamma[d * HH + lane + 64];
            const float be0 = beta[d * HH + lane];
            const float be1 = beta[d * HH + lane + 64];
            #pragma unroll
            for (int e = 0; e < EPW; ++e) {
                float s  = a0[e] + a1[e];
                float ss = a0[e] * a0[e] + a1[e] * a1[e];
                #pragma unroll
                for (int m = 1; m < 64; m <<= 1) {
                    s  += __shfl_xor(s, m, 64);
                    ss += __shfl_xor(ss, m, 64);
                }
                const float mu   = s * (1.0f / HH);
                const float var  = ss * (1.0f / HH) - mu * mu;
                const float rinv = rsqrtf(var + 1e-5f);
                a0[e] = fmaxf(0.0f, (a0[e] - mu) * rinv * g0 + be0);
                a1[e] = fmaxf(0.0f, (a1[e] - mu) * rinv * g1 + be1);
            }
        }

        // ---- Phase D: write h tile to LDS (overwrites x tile; same wave, safe) ----
        #pragma unroll
        for (int e = 0; e < EPW; ++e) {
            xw[e][lane]      = a0[e];
            xw[e][lane + 64] = a1[e];
        }
        __syncthreads();

        // ---- Phase E: y += h @ W2[d] ----
        const float* W2d = W2 + d * HH * HH;
        for (int h4 = 0; h4 < 32; ++h4) {
            float w0[4], w1[4];
            #pragma unroll
            for (int j = 0; j < 4; ++j) {
                w0[j] = W2d[(h4 * 4 + j) * HH + lane];
                w1[j] = W2d[(h4 * 4 + j) * HH + lane + 64];
            }
            #pragma unroll
            for (int e = 0; e < EPW; ++e) {
                const float4 hv = *(const float4*)&xw[e][h4 * 4];
                y0[e] = fmaf(hv.x, w0[0], y0[e]);
                y0[e] = fmaf(hv.y, w0[1], y0[e]);
                y0[e] = fmaf(hv.z, w0[2], y0[e]);
                y0[e] = fmaf(hv.w, w0[3], y0[e]);
                y1[e] = fmaf(hv.x, w1[0], y1[e]);
                y1[e] = fmaf(hv.y, w1[1], y1[e]);
                y1[e] = fmaf(hv.z, w1[2], y1[e]);
                y1[e] = fmaf(hv.w, w1[3], y1[e]);
            }
        }
        __syncthreads();   // next Phase A rewrites xw; also keeps waves in lockstep
    }

    // ---- store ----
    #pragma unroll
    for (int e = 0; e < EPW; ++e) {
        const int erow = ebase + eloc + e;
        out[erow * HH + lane]      = y0[e];
        out[erow * HH + lane + 64] = y1[e];
    }
}

} // namespace

extern "C" void kernel_launch(void* const* d_in, const int* in_sizes, int n_in,
                              void* d_out, int out_size, void* d_ws, size_t ws_size,
                              hipStream_t stream) {
    const float* source = (const float*)d_in[0];
    const float* target = (const float*)d_in[1];
    const int*   edge   = (const int*)  d_in[2];
    const float* freqs  = (const float*)d_in[3];
    const float* W1     = (const float*)d_in[4];
    const float* b1     = (const float*)d_in[5];
    const float* gammap = (const float*)d_in[6];
    const float* betap  = (const float*)d_in[7];
    const float* W2     = (const float*)d_in[8];
    const float* b2     = (const float*)d_in[9];
    float* out = (float*)d_out;

    const int E = in_sizes[2] / 2;     // edge is (2, E)
    const int nblocks = E / EPB;       // E = 200000 = 3125 * 64, exact

    rcpe_fused<<<dim3(nblocks), dim3(256), 0, stream>>>(
        source, target, edge, freqs, W1, b1, gammap, betap, W2, b2, out, E);
}

// Round 2
// 350.231 us; speedup vs baseline: 2.7806x; 2.7806x over previous
//
#include <hip/hip_runtime.h>
#include <math.h>

namespace {

typedef __attribute__((ext_vector_type(8))) short  short8;
typedef __attribute__((ext_vector_type(4))) float  float4v;

constexpr float PI_F     = 3.14159265358979323846f;
constexpr float TWO_PI_F = 6.28318530717958647692f;

constexpr int EPB = 64;          // edges per block
constexpr int W1T_ELEMS = 4 * 128 * 160;   // [d][n][k_pad]
constexpr int W2T_ELEMS = 4 * 128 * 128;   // [d][n][k]

__device__ __forceinline__ ushort rne_bf16(float x) {
    unsigned u = __float_as_uint(x);
    u += 0x7fffu + ((u >> 16) & 1u);
    return (ushort)(u >> 16);
}

// ---- prep: transpose + bf16-ify weights into workspace ----
__global__ void prep_weights(const float* __restrict__ W1,
                             const float* __restrict__ W2,
                             ushort* __restrict__ W1T,
                             ushort* __restrict__ W2T) {
    int idx = blockIdx.x * 256 + threadIdx.x;
    if (idx < W1T_ELEMS) {
        const int d = idx / (128 * 160);
        const int r = idx % (128 * 160);
        const int n = r / 160, k = r % 160;
        const float v = (k < 129) ? W1[(d * 129 + k) * 128 + n] : 0.0f;
        W1T[idx] = rne_bf16(v);
    } else {
        const int j = idx - W1T_ELEMS;
        if (j < W2T_ELEMS) {
            const int d = j / (128 * 128);
            const int r = j % (128 * 128);
            const int n = r / 128, k = r % 128;
            W2T[j] = rne_bf16(W2[(d * 128 + k) * 128 + n]);
        }
    }
}

// ---- main fused kernel ----
__global__ __launch_bounds__(256, 3)
void rcpe_mfma(const float* __restrict__ source,
               const float* __restrict__ target,
               const int*   __restrict__ edge,
               const float* __restrict__ freqs,
               const ushort* __restrict__ W1T,
               const float* __restrict__ b1,
               const float* __restrict__ gamma,
               const float* __restrict__ beta,
               const ushort* __restrict__ W2T,
               const float* __restrict__ b2,
               float* __restrict__ out,
               int E)
{
    __shared__ float feat_lds[EPB][4];
    __shared__ float freq_lds[4][64];
    __shared__ __align__(16) ushort h_lds[4][16][136];  // per-wave h tile, pad row to 136

    const int tid  = threadIdx.x;
    const int wave = tid >> 6;
    const int lane = tid & 63;
    const int m    = lane & 15;   // edge-within-tile (A row / C col group)
    const int s    = lane >> 4;   // k-segment / C row group
    const int ebase = blockIdx.x * EPB;
    const int eloc  = wave * 16;

    freq_lds[wave][lane] = freqs[tid];   // freqs is [4][64]

    if (tid < EPB) {
        const int e   = ebase + tid;
        const int s_i = edge[e];
        const int t_i = edge[E + e];
        const float sx = source[s_i * 3 + 0];
        const float sy = source[s_i * 3 + 1];
        const float sh = source[s_i * 3 + 2];
        const float tx = target[t_i * 5 + 0];
        const float ty = target[t_i * 5 + 1];
        const float th = target[t_i * 5 + 2];
        const float ts = target[t_i * 5 + 3];
        const float dx = sx - tx;
        const float dy = sy - ty;
        float a = sh - th + PI_F;
        a = fmodf(a, TWO_PI_F);
        if (a < 0.0f) a += TWO_PI_F;
        const float dh  = a - PI_F;
        const float ang = atan2f(dy, dx);
        const float tvx = ts * cosf(th);
        const float tvy = ts * sinf(th);
        const float closing = tvx * cosf(ang) + tvy * sinf(ang);
        feat_lds[tid][0] = dx;
        feat_lds[tid][1] = dy;
        feat_lds[tid][2] = dh;
        feat_lds[tid][3] = closing;
    }
    __syncthreads();

    // persistent y accumulators (C layout): y[t] = tile cols m+16t, rows s*4+r
    float4v y[8];
    #pragma unroll
    for (int t = 0; t < 8; ++t) {
        const int col = m + 16 * t;
        float v = 0.0f;
        #pragma unroll
        for (int d = 0; d < 4; ++d) v += b2[d * 128 + col];
        y[t] = (float4v){v, v, v, v};
    }

    for (int d = 0; d < 4; ++d) {
        const float fe = feat_lds[eloc + m][d];

        // ---- A fragments for GEMM1: x[e][k], lane m=edge, k=(s*8+j)+32*ks ----
        short8 afrag[5];
        #pragma unroll
        for (int h = 0; h < 2; ++h) {
            #pragma unroll
            for (int j = 0; j < 8; ++j) {
                const float fr  = freq_lds[d][s * 8 + 32 * h + j];
                const float ang = fe * fr * TWO_PI_F;
                float sn, cs;
                __sincosf(ang, &sn, &cs);
                afrag[h][j]     = (short)rne_bf16(cs);   // ksteps 0,1: cos
                afrag[h + 2][j] = (short)rne_bf16(sn);   // ksteps 2,3: sin
            }
        }
        {   // kstep 4: k=128 is raw feature (lane s==0, j==0); k>128 weights are 0
            short8 z = (short8)(short)0;
            if (s == 0) z[0] = (short)rne_bf16(fe);
            afrag[4] = z;
        }

        // ---- GEMM1: h = x @ W1[d] + b1[d] ----
        float4v hacc[8];
        #pragma unroll
        for (int t = 0; t < 8; ++t) {
            const float bb = b1[d * 128 + m + 16 * t];
            hacc[t] = (float4v){bb, bb, bb, bb};
        }
        const ushort* w1base = W1T + d * 128 * 160;
        #pragma unroll
        for (int t = 0; t < 8; ++t) {
            const ushort* wp = w1base + (t * 16 + m) * 160 + s * 8;
            #pragma unroll
            for (int ks = 0; ks < 5; ++ks) {
                const short8 bfrag = *(const short8*)(wp + ks * 32);
                hacc[t] = __builtin_amdgcn_mfma_f32_16x16x32_bf16(afrag[ks], bfrag, hacc[t], 0, 0, 0);
            }
        }

        // ---- LayerNorm + ReLU on C-layout regs ----
        float mu[4], rinv[4];
        #pragma unroll
        for (int r = 0; r < 4; ++r) {
            float sm = 0.0f, sq = 0.0f;
            #pragma unroll
            for (int t = 0; t < 8; ++t) { const float v = hacc[t][r]; sm += v; sq += v * v; }
            #pragma unroll
            for (int msk = 1; msk < 16; msk <<= 1) {
                sm += __shfl_xor(sm, msk, 64);
                sq += __shfl_xor(sq, msk, 64);
            }
            mu[r] = sm * (1.0f / 128.0f);
            const float var = sq * (1.0f / 128.0f) - mu[r] * mu[r];
            rinv[r] = rsqrtf(var + 1e-5f);
        }
        #pragma unroll
        for (int t = 0; t < 8; ++t) {
            const int col = m + 16 * t;
            const float g  = gamma[d * 128 + col];
            const float be = beta[d * 128 + col];
            #pragma unroll
            for (int r = 0; r < 4; ++r) {
                float v = (hacc[t][r] - mu[r]) * rinv[r] * g + be;
                v = fmaxf(v, 0.0f);
                h_lds[wave][s * 4 + r][col] = rne_bf16(v);
            }
        }
        __syncthreads();

        // ---- GEMM2: y += h @ W2[d] (h re-read as A fragments) ----
        short8 areg[4];
        #pragma unroll
        for (int ks = 0; ks < 4; ++ks)
            areg[ks] = *(const short8*)&h_lds[wave][m][ks * 32 + s * 8];

        const ushort* w2base = W2T + d * 128 * 128;
        #pragma unroll
        for (int t = 0; t < 8; ++t) {
            const ushort* wp = w2base + (t * 16 + m) * 128 + s * 8;
            #pragma unroll
            for (int ks = 0; ks < 4; ++ks) {
                const short8 bfrag = *(const short8*)(wp + ks * 32);
                y[t] = __builtin_amdgcn_mfma_f32_16x16x32_bf16(areg[ks], bfrag, y[t], 0, 0, 0);
            }
        }
        __syncthreads();   // protect h_lds before next-d rewrite
    }

    // ---- store (C layout): row = edge s*4+r, col = m+16t ----
    #pragma unroll
    for (int t = 0; t < 8; ++t) {
        #pragma unroll
        for (int r = 0; r < 4; ++r) {
            out[(ebase + eloc + s * 4 + r) * 128 + m + 16 * t] = y[t][r];
        }
    }
}

} // namespace

extern "C" void kernel_launch(void* const* d_in, const int* in_sizes, int n_in,
                              void* d_out, int out_size, void* d_ws, size_t ws_size,
                              hipStream_t stream) {
    const float* source = (const float*)d_in[0];
    const float* target = (const float*)d_in[1];
    const int*   edge   = (const int*)  d_in[2];
    const float* freqs  = (const float*)d_in[3];
    const float* W1     = (const float*)d_in[4];
    const float* b1     = (const float*)d_in[5];
    const float* gammap = (const float*)d_in[6];
    const float* betap  = (const float*)d_in[7];
    const float* W2     = (const float*)d_in[8];
    const float* b2     = (const float*)d_in[9];
    float* out = (float*)d_out;

    ushort* W1T = (ushort*)d_ws;                       // 163840 B
    ushort* W2T = (ushort*)((char*)d_ws + W1T_ELEMS * 2);  // 131072 B

    const int E = in_sizes[2] / 2;     // edge is (2, E); E = 200000
    const int nblocks = E / EPB;       // 3125, exact

    const int prep_total = W1T_ELEMS + W2T_ELEMS;      // 147456
    prep_weights<<<dim3((prep_total + 255) / 256), dim3(256), 0, stream>>>(W1, W2, W1T, W2T);

    rcpe_mfma<<<dim3(nblocks), dim3(256), 0, stream>>>(
        source, target, edge, freqs, W1T, b1, gammap, betap, W2T, b2, out, E);
}

// Round 3
// 304.809 us; speedup vs baseline: 3.1949x; 1.1490x over previous
//
#include <hip/hip_runtime.h>
#include <hip/hip_bf16.h>
#include <math.h>

namespace {

typedef __attribute__((ext_vector_type(8)))  short short8;
typedef __attribute__((ext_vector_type(16))) float f32x16;
typedef __attribute__((ext_vector_type(4)))  float float4v;

constexpr float PI_F     = 3.14159265358979323846f;
constexpr float TWO_PI_F = 6.28318530717958647692f;

__device__ __forceinline__ unsigned pack2(float a, float b) {
    __hip_bfloat162 h = __float22bfloat162_rn(float2{a, b});
    unsigned r;
    __builtin_memcpy(&r, &h, 4);
    return r;
}

union Frag {
    unsigned u[4];
    short8   s;
};

// ---- prep: transpose + bf16-ify weights: W1T[d][n][k], W2T[d][n][k] ----
__global__ __launch_bounds__(256)
void prep_weights(const float* __restrict__ W1,
                  const float* __restrict__ W2,
                  ushort* __restrict__ W1T,
                  ushort* __restrict__ W2T) {
    const int idx = blockIdx.x * 256 + threadIdx.x;   // 0 .. 131071
    const int r = idx & 0xFFFF;                        // d*16384 + n*128 + k
    const int d = r >> 14;
    const int n = (r >> 7) & 127;
    const int k = r & 127;
    if (idx < 65536) {
        __hip_bfloat16 v = __float2bfloat16(W1[(d * 129 + k) * 128 + n]);
        ushort u; __builtin_memcpy(&u, &v, 2);
        W1T[r] = u;
    } else {
        __hip_bfloat16 v = __float2bfloat16(W2[(d * 128 + k) * 128 + n]);
        ushort u; __builtin_memcpy(&u, &v, 2);
        W2T[r] = u;
    }
}

// ---- main fused kernel: transposed (h^T = W1^T x^T ; y^T = W2^T h^T) ----
// wave = 32 edges (C cols). lane: e5 = lane&31 (edge / weight-row), s1 = lane>>5.
// C layout (32x32): col = lane&31, row = (reg&3) + 8*(reg>>2) + 4*s1.
__global__ __launch_bounds__(128, 2)
void rcpe_mfma32(const float* __restrict__ source,
                 const float* __restrict__ target,
                 const int*   __restrict__ edge,
                 const float* __restrict__ freqs,
                 const float* __restrict__ W1,      // f32, for k=128 rank-1 row
                 const ushort* __restrict__ W1T,
                 const float* __restrict__ b1,
                 const float* __restrict__ gamma,
                 const float* __restrict__ beta,
                 const ushort* __restrict__ W2T,
                 const float* __restrict__ b2,
                 float* __restrict__ out,
                 int E)
{
    __shared__ __align__(16) float feat_lds[4][64];
    __shared__ __align__(16) float freq_lds[4][64];

    const int tid  = threadIdx.x;
    const int wv   = tid >> 6;
    const int lane = tid & 63;
    const int e5   = lane & 31;
    const int s1   = lane >> 5;
    const bool hi  = (s1 != 0);
    const int ebase = blockIdx.x * 64;

    // stage freqs (4x64 f32 = 256, 128 threads x2)
    ((float*)freq_lds)[tid]       = freqs[tid];
    ((float*)freq_lds)[tid + 128] = freqs[tid + 128];

    // stage features (one thread per edge), d-major for conflict-free reads
    if (tid < 64) {
        const int e   = ebase + tid;
        const int s_i = edge[e];
        const int t_i = edge[E + e];
        const float sx = source[s_i * 3 + 0];
        const float sy = source[s_i * 3 + 1];
        const float sh = source[s_i * 3 + 2];
        const float tx = target[t_i * 5 + 0];
        const float ty = target[t_i * 5 + 1];
        const float th = target[t_i * 5 + 2];
        const float ts = target[t_i * 5 + 3];
        const float dx = sx - tx;
        const float dy = sy - ty;
        float a = sh - th + PI_F;
        a = fmodf(a, TWO_PI_F);
        if (a < 0.0f) a += TWO_PI_F;
        const float dh  = a - PI_F;
        const float ang = atan2f(dy, dx);
        const float tvx = ts * cosf(th);
        const float tvy = ts * sinf(th);
        const float closing = tvx * cosf(ang) + tvy * sinf(ang);
        feat_lds[0][tid] = dx;
        feat_lds[1][tid] = dy;
        feat_lds[2][tid] = dh;
        feat_lds[3][tid] = closing;
    }
    __syncthreads();   // the only barrier

    const int eg = ebase + wv * 32 + e5;   // this lane's edge (column role)

    // ---- y init: sum_d b2, in C2 layout ----
    f32x16 y[4];
    #pragma unroll
    for (int t = 0; t < 4; ++t) {
        #pragma unroll
        for (int rh = 0; rh < 4; ++rh) {
            float4v a = {0.f, 0.f, 0.f, 0.f};
            #pragma unroll
            for (int d = 0; d < 4; ++d) {
                const float4v bv = *(const float4v*)(b2 + d * 128 + 32 * t + 4 * s1 + 8 * rh);
                #pragma unroll
                for (int rl = 0; rl < 4; ++rl) a[rl] += bv[rl];
            }
            #pragma unroll
            for (int rl = 0; rl < 4; ++rl) y[t][4 * rh + rl] = a[rl];
        }
    }

    #pragma unroll 1
    for (int d = 0; d < 4; ++d) {
        const float fe = feat_lds[d][wv * 32 + e5];

        // ---- x fragments (B of GEMM1): elem j of kstep ks = channel 16ks+8s1+j ----
        Frag xf[8];
        #pragma unroll
        for (int kc = 0; kc < 4; ++kc) {
            const float4v f0 = *(const float4v*)(&freq_lds[d][16 * kc + 8 * s1]);
            const float4v f1 = *(const float4v*)(&freq_lds[d][16 * kc + 8 * s1 + 4]);
            float fr[8] = {f0[0], f0[1], f0[2], f0[3], f1[0], f1[1], f1[2], f1[3]};
            float cs[8], sn[8];
            #pragma unroll
            for (int j = 0; j < 8; ++j) {
                const float tv = __builtin_amdgcn_fractf(fe * fr[j]);  // revolutions, [0,1)
                sn[j] = __builtin_amdgcn_sinf(tv);
                cs[j] = __builtin_amdgcn_cosf(tv);
            }
            #pragma unroll
            for (int jp = 0; jp < 4; ++jp) {
                xf[kc].u[jp]     = pack2(cs[2 * jp], cs[2 * jp + 1]);
                xf[kc + 4].u[jp] = pack2(sn[2 * jp], sn[2 * jp + 1]);
            }
        }

        // ---- GEMM1: hacc = b1 ; hacc += W1^T x^T ----
        f32x16 hacc[4];
        #pragma unroll
        for (int t = 0; t < 4; ++t) {
            #pragma unroll
            for (int rh = 0; rh < 4; ++rh) {
                const float4v bv = *(const float4v*)(b1 + d * 128 + 32 * t + 4 * s1 + 8 * rh);
                #pragma unroll
                for (int rl = 0; rl < 4; ++rl) hacc[t][4 * rh + rl] = bv[rl];
            }
        }
        const ushort* w1p = W1T + (d * 128 + e5) * 128 + 8 * s1;
        #pragma unroll
        for (int ks = 0; ks < 8; ++ks) {
            const short8 bx = xf[ks].s;
            #pragma unroll
            for (int t = 0; t < 4; ++t) {
                const short8 aw = *(const short8*)(w1p + t * 4096 + ks * 16);
                hacc[t] = __builtin_amdgcn_mfma_f32_32x32x16_bf16(aw, bx, hacc[t], 0, 0, 0);
            }
        }

        // ---- rank-1: k=128 raw-feature column, exact f32 ----
        const float* w1r = W1 + (d * 129 + 128) * 128 + 4 * s1;
        #pragma unroll
        for (int t = 0; t < 4; ++t) {
            #pragma unroll
            for (int rh = 0; rh < 4; ++rh) {
                const float4v wv4 = *(const float4v*)(w1r + 32 * t + 8 * rh);
                #pragma unroll
                for (int rl = 0; rl < 4; ++rl)
                    hacc[t][4 * rh + rl] = fmaf(fe, wv4[rl], hacc[t][4 * rh + rl]);
            }
        }

        // ---- LayerNorm + ReLU (channels = rows; partner lane holds other 64) ----
        float sm = 0.f, sq = 0.f;
        #pragma unroll
        for (int t = 0; t < 4; ++t) {
            #pragma unroll
            for (int r = 0; r < 16; ++r) {
                const float v = hacc[t][r];
                sm += v;
                sq = fmaf(v, v, sq);
            }
        }
        sm += __shfl_xor(sm, 32, 64);
        sq += __shfl_xor(sq, 32, 64);
        const float mu   = sm * (1.f / 128.f);
        const float var  = sq * (1.f / 128.f) - mu * mu;
        const float rinv = rsqrtf(var + 1e-5f);
        #pragma unroll
        for (int t = 0; t < 4; ++t) {
            #pragma unroll
            for (int rh = 0; rh < 4; ++rh) {
                const float4v gv = *(const float4v*)(gamma + d * 128 + 32 * t + 4 * s1 + 8 * rh);
                const float4v bv = *(const float4v*)(beta  + d * 128 + 32 * t + 4 * s1 + 8 * rh);
                #pragma unroll
                for (int rl = 0; rl < 4; ++rl) {
                    float v = (hacc[t][4 * rh + rl] - mu) * rinv;
                    v = fmaf(v, gv[rl], bv[rl]);
                    hacc[t][4 * rh + rl] = fmaxf(v, 0.f);
                }
            }
        }

        // ---- GEMM2: y += W2^T h^T; B-frag built via pack + xor-32 shuffle ----
        const ushort* w2p = W2T + (d * 128 + e5) * 128 + 8 * s1;
        #pragma unroll
        for (int ks = 0; ks < 8; ++ks) {
            const int t  = ks >> 1;
            const int k1 = ks & 1;
            const unsigned A0 = pack2(hacc[t][8 * k1 + 0], hacc[t][8 * k1 + 1]); // rh=2k1, rl 0,1
            const unsigned A1 = pack2(hacc[t][8 * k1 + 2], hacc[t][8 * k1 + 3]); // rh=2k1, rl 2,3
            const unsigned B0 = pack2(hacc[t][8 * k1 + 4], hacc[t][8 * k1 + 5]); // rh=2k1+1
            const unsigned B1 = pack2(hacc[t][8 * k1 + 6], hacc[t][8 * k1 + 7]);
            const unsigned send0 = hi ? A0 : B0;
            const unsigned send1 = hi ? A1 : B1;
            const unsigned r0 = (unsigned)__shfl_xor((int)send0, 32, 64);
            const unsigned r1 = (unsigned)__shfl_xor((int)send1, 32, 64);
            const unsigned self0 = hi ? B0 : A0;
            const unsigned self1 = hi ? B1 : A1;
            Frag bh;
            bh.u[0] = hi ? r0 : self0;
            bh.u[1] = hi ? r1 : self1;
            bh.u[2] = hi ? self0 : r0;
            bh.u[3] = hi ? self1 : r1;
            #pragma unroll
            for (int t2 = 0; t2 < 4; ++t2) {
                const short8 aw = *(const short8*)(w2p + t2 * 4096 + ks * 16);
                y[t2] = __builtin_amdgcn_mfma_f32_32x32x16_bf16(aw, bh.s, y[t2], 0, 0, 0);
            }
        }
    }

    // ---- store (C2 layout): out channel = 32t + 4s1 + 8rh + rl, edge = eg ----
    #pragma unroll
    for (int t = 0; t < 4; ++t) {
        #pragma unroll
        for (int rh = 0; rh < 4; ++rh) {
            float4v o;
            #pragma unroll
            for (int rl = 0; rl < 4; ++rl) o[rl] = y[t][4 * rh + rl];
            *(float4v*)(out + eg * 128 + 32 * t + 4 * s1 + 8 * rh) = o;
        }
    }
}

} // namespace

extern "C" void kernel_launch(void* const* d_in, const int* in_sizes, int n_in,
                              void* d_out, int out_size, void* d_ws, size_t ws_size,
                              hipStream_t stream) {
    const float* source = (const float*)d_in[0];
    const float* target = (const float*)d_in[1];
    const int*   edge   = (const int*)  d_in[2];
    const float* freqs  = (const float*)d_in[3];
    const float* W1     = (const float*)d_in[4];
    const float* b1     = (const float*)d_in[5];
    const float* gammap = (const float*)d_in[6];
    const float* betap  = (const float*)d_in[7];
    const float* W2     = (const float*)d_in[8];
    const float* b2     = (const float*)d_in[9];
    float* out = (float*)d_out;

    ushort* W1T = (ushort*)d_ws;                            // 4*128*128*2 = 131072 B
    ushort* W2T = (ushort*)((char*)d_ws + 65536 * 2);       // 131072 B

    const int E = in_sizes[2] / 2;      // edge is (2, E); E = 200000

    prep_weights<<<dim3(512), dim3(256), 0, stream>>>(W1, W2, W1T, W2T);

    rcpe_mfma32<<<dim3(E / 64), dim3(128), 0, stream>>>(
        source, target, edge, freqs, W1, W1T, b1, gammap, betap, W2T, b2, out, E);
}

// Round 4
// 195.194 us; speedup vs baseline: 4.9891x; 1.5616x over previous
//
#include <hip/hip_runtime.h>
#include <hip/hip_bf16.h>
#include <math.h>

namespace {

typedef __attribute__((ext_vector_type(8))) short  short8;
typedef __attribute__((ext_vector_type(4))) float  float4v;

constexpr float PI_F     = 3.14159265358979323846f;
constexpr float TWO_PI_F = 6.28318530717958647692f;

__device__ __forceinline__ unsigned pack2(float a, float b) {
    __hip_bfloat162 h = __float22bfloat162_rn(float2{a, b});
    unsigned r;
    __builtin_memcpy(&r, &h, 4);
    return r;
}

union Frag {
    unsigned u[4];
    short8   s;
};

__device__ __forceinline__ void gl2lds16(const void* g, void* l) {
    __builtin_amdgcn_global_load_lds(
        (const __attribute__((address_space(1))) void*)g,
        (__attribute__((address_space(3))) void*)l, 16, 0, 0);
}

// ---- prep: transpose + bf16-ify weights: W1T[d][n][k], W2T[d][n][k] (k<128) ----
__global__ __launch_bounds__(256)
void prep_weights(const float* __restrict__ W1,
                  const float* __restrict__ W2,
                  ushort* __restrict__ W1T,
                  ushort* __restrict__ W2T) {
    const int idx = blockIdx.x * 256 + threadIdx.x;   // 0 .. 131071
    const int r = idx & 0xFFFF;                        // d*16384 + n*128 + k
    const int d = r >> 14;
    const int n = (r >> 7) & 127;
    const int k = r & 127;
    if (idx < 65536) {
        __hip_bfloat16 v = __float2bfloat16(W1[(d * 129 + k) * 128 + n]);
        ushort u; __builtin_memcpy(&u, &v, 2);
        W1T[r] = u;
    } else {
        __hip_bfloat16 v = __float2bfloat16(W2[(d * 128 + k) * 128 + n]);
        ushort u; __builtin_memcpy(&u, &v, 2);
        W2T[r] = u;
    }
}

// ---- main fused kernel ----
// 4 waves x 16 edges = 64 edges/block. Transposed math: h^T = W1^T x^T.
// 16x16x32 MFMA. A (weights): row = lane&15 (=ch%16), k = (lane>>4)*8+j+32ks.
// B (x / h):   col = lane&15 (=edge), k = (lane>>4)*8+j+32ks.
// C: col = lane&15 (=edge), row(ch) = 16t + 4*(lane>>4) + reg.
__global__ __launch_bounds__(256, 4)
void rcpe_mfma16(const float* __restrict__ source,
                 const float* __restrict__ target,
                 const int*   __restrict__ edge,
                 const float* __restrict__ freqs,
                 const float* __restrict__ W1,      // f32, for k=128 rank-1 row
                 const ushort* __restrict__ W1T,
                 const float* __restrict__ b1,
                 const float* __restrict__ gamma,
                 const float* __restrict__ beta,
                 const ushort* __restrict__ W2T,
                 const float* __restrict__ b2,
                 float* __restrict__ out,
                 int E)
{
    __shared__ __align__(16) ushort wbuf[2048 * 8];   // 32 KB weight stage, frag-linear
    __shared__ __align__(16) float feat_lds[4][64];
    __shared__ __align__(16) float freq_lds[4][64];

    const int tid  = threadIdx.x;
    const int wv   = tid >> 6;
    const int lane = tid & 63;
    const int e4   = lane & 15;
    const int g    = lane >> 4;        // 0..3
    const int hiT  = g >> 1;
    const int ebase = blockIdx.x * 64;
    const int eg    = ebase + wv * 16 + e4;

    // shuffle source lanes for GEMM2 B-frag assembly
    const int srcA = e4 + (((2 * g) & 3) << 4);
    const int srcB = e4 + (((2 * g + 1) & 3) << 4);

    ((float*)freq_lds)[tid] = freqs[tid];   // freqs is [4][64] = 256

    if (tid < 64) {
        const int e   = ebase + tid;
        const int s_i = edge[e];
        const int t_i = edge[E + e];
        const float sx = source[s_i * 3 + 0];
        const float sy = source[s_i * 3 + 1];
        const float sh = source[s_i * 3 + 2];
        const float tx = target[t_i * 5 + 0];
        const float ty = target[t_i * 5 + 1];
        const float th = target[t_i * 5 + 2];
        const float ts = target[t_i * 5 + 3];
        const float dx = sx - tx;
        const float dy = sy - ty;
        float a = sh - th + PI_F;
        a = fmodf(a, TWO_PI_F);
        if (a < 0.0f) a += TWO_PI_F;
        const float dh  = a - PI_F;
        const float ang = atan2f(dy, dx);
        const float tvx = ts * cosf(th);
        const float tvy = ts * sinf(th);
        const float closing = tvx * cosf(ang) + tvy * sinf(ang);
        feat_lds[0][tid] = dx;
        feat_lds[1][tid] = dy;
        feat_lds[2][tid] = dh;
        feat_lds[3][tid] = closing;
    }
    __syncthreads();

    // ---- y init: sum_d b2 (C layout: ch = 16t + 4g + r) ----
    float4v y[8];
    #pragma unroll
    for (int t = 0; t < 8; ++t) {
        float4v a = {0.f, 0.f, 0.f, 0.f};
        #pragma unroll
        for (int d = 0; d < 4; ++d) {
            const float4v bv = *(const float4v*)(b2 + d * 128 + 16 * t + 4 * g);
            #pragma unroll
            for (int r = 0; r < 4; ++r) a[r] += bv[r];
        }
        y[t] = a;
    }

    #pragma unroll 1
    for (int d = 0; d < 4; ++d) {
        const float fe = feat_lds[d][wv * 16 + e4];

        // ---- trig: 16 angles fill 4 B-frags (ks0=cosLo, ks1=cosHi, ks2=sinLo, ks3=sinHi)
        Frag xf[4];
        {
            float cl[8], sl[8], ch8[8], sh8[8];
            #pragma unroll
            for (int j = 0; j < 8; ++j) {
                const float frL = freq_lds[d][8 * g + j];
                const float frH = freq_lds[d][32 + 8 * g + j];
                const float tL = __builtin_amdgcn_fractf(fe * frL);
                const float tH = __builtin_amdgcn_fractf(fe * frH);
                sl[j]  = __builtin_amdgcn_sinf(tL);
                cl[j]  = __builtin_amdgcn_cosf(tL);
                sh8[j] = __builtin_amdgcn_sinf(tH);
                ch8[j] = __builtin_amdgcn_cosf(tH);
            }
            #pragma unroll
            for (int p = 0; p < 4; ++p) {
                xf[0].u[p] = pack2(cl[2 * p],  cl[2 * p + 1]);
                xf[1].u[p] = pack2(ch8[2 * p], ch8[2 * p + 1]);
                xf[2].u[p] = pack2(sl[2 * p],  sl[2 * p + 1]);
                xf[3].u[p] = pack2(sh8[2 * p], sh8[2 * p + 1]);
            }
        }

        __syncthreads();   // all waves done reading wbuf (prev d's W2)

        // ---- stage W1[d] into LDS, frag-linear: chunk (t*4+ks)*64+lane ----
        #pragma unroll
        for (int p = 0; p < 8; ++p) {
            const int t  = 2 * wv + (p >> 2);
            const int ks = p & 3;
            const ushort* gp = W1T + ((d * 128 + 16 * t + e4) * 128 + g * 8 + 32 * ks);
            gl2lds16(gp, &wbuf[(t * 4 + ks) * 512]);
        }
        __syncthreads();   // drains vmcnt, W1 visible

        // ---- GEMM1: hacc[t] = b1 + W1^T x^T ----
        float4v hacc[8];
        #pragma unroll
        for (int t = 0; t < 8; ++t) {
            const float4v bv = *(const float4v*)(b1 + d * 128 + 16 * t + 4 * g);
            float4v acc = {bv[0], bv[1], bv[2], bv[3]};
            #pragma unroll
            for (int ks = 0; ks < 4; ++ks) {
                const short8 aw = *(const short8*)&wbuf[(t * 4 + ks) * 512 + lane * 8];
                acc = __builtin_amdgcn_mfma_f32_16x16x32_bf16(aw, xf[ks].s, acc, 0, 0, 0);
            }
            hacc[t] = acc;
        }

        // ---- rank-1: k=128 raw-feature column, exact f32 ----
        const float* w1r = W1 + (d * 129 + 128) * 128 + 4 * g;
        #pragma unroll
        for (int t = 0; t < 8; ++t) {
            const float4v wv4 = *(const float4v*)(w1r + 16 * t);
            #pragma unroll
            for (int r = 0; r < 4; ++r)
                hacc[t][r] = fmaf(fe, wv4[r], hacc[t][r]);
        }

        // ---- LayerNorm + ReLU (reduce over g-lanes: xor 16, 32) ----
        float sm = 0.f, sq = 0.f;
        #pragma unroll
        for (int t = 0; t < 8; ++t) {
            #pragma unroll
            for (int r = 0; r < 4; ++r) {
                const float v = hacc[t][r];
                sm += v;
                sq = fmaf(v, v, sq);
            }
        }
        sm += __shfl_xor(sm, 16, 64);
        sq += __shfl_xor(sq, 16, 64);
        sm += __shfl_xor(sm, 32, 64);
        sq += __shfl_xor(sq, 32, 64);
        const float mu   = sm * (1.f / 128.f);
        const float var  = sq * (1.f / 128.f) - mu * mu;
        const float rinv = rsqrtf(var + 1e-5f);
        #pragma unroll
        for (int t = 0; t < 8; ++t) {
            const float4v gv = *(const float4v*)(gamma + d * 128 + 16 * t + 4 * g);
            const float4v bv = *(const float4v*)(beta  + d * 128 + 16 * t + 4 * g);
            #pragma unroll
            for (int r = 0; r < 4; ++r) {
                float v = (hacc[t][r] - mu) * rinv;
                v = fmaf(v, gv[r], bv[r]);
                hacc[t][r] = fmaxf(v, 0.f);
            }
        }

        __syncthreads();   // all waves done reading W1 from wbuf

        // ---- stage W2[d] (same frag-linear layout) ----
        #pragma unroll
        for (int p = 0; p < 8; ++p) {
            const int t  = 2 * wv + (p >> 2);
            const int ks = p & 3;
            const ushort* gp = W2T + ((d * 128 + 16 * t + e4) * 128 + g * 8 + 32 * ks);
            gl2lds16(gp, &wbuf[(t * 4 + ks) * 512]);
        }

        // ---- while W2 stages: assemble GEMM2 B-frags from hacc via shuffles ----
        // target (g,ks) elem j: ch = 32ks + 8g + j; src reg t=2ks+(g>>1);
        // j0..3 from lane srcA (g'=(2g)&3), j4..7 from srcB (g'=(2g+1)&3).
        Frag bfr[4];
        #pragma unroll
        for (int ks = 0; ks < 4; ++ks) {
            const int tE = 2 * ks, tO = tE + 1;
            const unsigned pkE0 = pack2(hacc[tE][0], hacc[tE][1]);
            const unsigned pkE1 = pack2(hacc[tE][2], hacc[tE][3]);
            const unsigned pkO0 = pack2(hacc[tO][0], hacc[tO][1]);
            const unsigned pkO1 = pack2(hacc[tO][2], hacc[tO][3]);
            const unsigned aE0 = (unsigned)__shfl((int)pkE0, srcA, 64);
            const unsigned aE1 = (unsigned)__shfl((int)pkE1, srcA, 64);
            const unsigned aO0 = (unsigned)__shfl((int)pkO0, srcA, 64);
            const unsigned aO1 = (unsigned)__shfl((int)pkO1, srcA, 64);
            const unsigned bE0 = (unsigned)__shfl((int)pkE0, srcB, 64);
            const unsigned bE1 = (unsigned)__shfl((int)pkE1, srcB, 64);
            const unsigned bO0 = (unsigned)__shfl((int)pkO0, srcB, 64);
            const unsigned bO1 = (unsigned)__shfl((int)pkO1, srcB, 64);
            bfr[ks].u[0] = hiT ? aO0 : aE0;
            bfr[ks].u[1] = hiT ? aO1 : aE1;
            bfr[ks].u[2] = hiT ? bO0 : bE0;
            bfr[ks].u[3] = hiT ? bO1 : bE1;
        }

        __syncthreads();   // W2 staged & visible

        // ---- GEMM2: y += W2^T h^T ----
        #pragma unroll
        for (int t = 0; t < 8; ++t) {
            float4v acc = y[t];
            #pragma unroll
            for (int ks = 0; ks < 4; ++ks) {
                const short8 aw = *(const short8*)&wbuf[(t * 4 + ks) * 512 + lane * 8];
                acc = __builtin_amdgcn_mfma_f32_16x16x32_bf16(aw, bfr[ks].s, acc, 0, 0, 0);
            }
            y[t] = acc;
        }
    }

    // ---- store: per t one float4 -> 4 g-lanes form a full 64B sector per edge ----
    #pragma unroll
    for (int t = 0; t < 8; ++t) {
        *(float4v*)(out + eg * 128 + 16 * t + 4 * g) = y[t];
    }
}

} // namespace

extern "C" void kernel_launch(void* const* d_in, const int* in_sizes, int n_in,
                              void* d_out, int out_size, void* d_ws, size_t ws_size,
                              hipStream_t stream) {
    const float* source = (const float*)d_in[0];
    const float* target = (const float*)d_in[1];
    const int*   edge   = (const int*)  d_in[2];
    const float* freqs  = (const float*)d_in[3];
    const float* W1     = (const float*)d_in[4];
    const float* b1     = (const float*)d_in[5];
    const float* gammap = (const float*)d_in[6];
    const float* betap  = (const float*)d_in[7];
    const float* W2     = (const float*)d_in[8];
    const float* b2     = (const float*)d_in[9];
    float* out = (float*)d_out;

    ushort* W1T = (ushort*)d_ws;                       // 131072 B
    ushort* W2T = (ushort*)((char*)d_ws + 131072);     // 131072 B

    const int E = in_sizes[2] / 2;      // edge is (2, E); E = 200000

    prep_weights<<<dim3(512), dim3(256), 0, stream>>>(W1, W2, W1T, W2T);

    rcpe_mfma16<<<dim3(E / 64), dim3(256), 0, stream>>>(
        source, target, edge, freqs, W1, W1T, b1, gammap, betap, W2T, b2, out, E);
}

// Round 5
// 113.719 us; speedup vs baseline: 8.5636x; 1.7165x over previous
//
#include <hip/hip_runtime.h>
#include <hip/hip_bf16.h>
#include <math.h>

namespace {

typedef __attribute__((ext_vector_type(8))) short  short8;
typedef __attribute__((ext_vector_type(4))) float  float4v;

constexpr float PI_F     = 3.14159265358979323846f;
constexpr float TWO_PI_F = 6.28318530717958647692f;

__device__ __forceinline__ unsigned pack2(float a, float b) {
    __hip_bfloat162 h = __float22bfloat162_rn(float2{a, b});
    unsigned r;
    __builtin_memcpy(&r, &h, 4);
    return r;
}

union Frag {
    unsigned u[4];
    short8   s;
};

__device__ __forceinline__ void gl2lds16(const void* g, void* l) {
    __builtin_amdgcn_global_load_lds(
        (const __attribute__((address_space(1))) void*)g,
        (__attribute__((address_space(3))) void*)l, 16, 0, 0);
}

// ---- prep: transpose + bf16 weights.
// W1T[d][n][k]   = W1[d][k][n]               (k < 128; k=128 handled as f32 rank-1)
// W2T[d][n][ks_] = W2[d][pi(ks_)][n]  with pi chosen so GEMM2's B-frag is lane-local:
//   pi(kslot) = 32*(kslot>>5) + 16*((kslot>>2)&1) + 4*((kslot>>3)&3) + (kslot&3)
__global__ __launch_bounds__(256)
void prep_weights(const float* __restrict__ W1,
                  const float* __restrict__ W2,
                  ushort* __restrict__ W1T,
                  ushort* __restrict__ W2T) {
    const int idx = blockIdx.x * 256 + threadIdx.x;   // 0 .. 131071
    if (idx < 65536) {
        const int d = idx >> 14;
        const int n = (idx >> 7) & 127;
        const int k = idx & 127;
        __hip_bfloat16 v = __float2bfloat16(W1[(d * 129 + k) * 128 + n]);
        ushort u; __builtin_memcpy(&u, &v, 2);
        W1T[idx] = u;
    } else {
        const int j = idx - 65536;
        const int d = j >> 14;
        const int n = (j >> 7) & 127;
        const int kslot = j & 127;
        const int c = 32 * (kslot >> 5) + 16 * ((kslot >> 2) & 1)
                    + 4 * ((kslot >> 3) & 3) + (kslot & 3);
        __hip_bfloat16 v = __float2bfloat16(W2[(d * 128 + c) * 128 + n]);
        ushort u; __builtin_memcpy(&u, &v, 2);
        W2T[j] = u;
    }
}

// stage one 32KB weight tile (frag-linear chunks) — wave wv stages t = wv
__device__ __forceinline__ void stage_tile(const ushort* __restrict__ Wsrc,
                                           ushort* dst, int wv, int lane) {
    const int e4 = lane & 15;
    const int g  = lane >> 4;
    #pragma unroll
    for (int ks = 0; ks < 4; ++ks) {
        const ushort* gp = Wsrc + ((16 * wv + e4) * 128 + g * 8 + 32 * ks);
        gl2lds16(gp, dst + (wv * 4 + ks) * 512);
    }
}

// ---- main fused kernel ----
// 8 waves x 16 edges = 128 edges/block. Transposed math: h^T = W1^T x^T.
// 16x16x32 MFMA. A (weights): row = lane&15 (ch%16), kslot = (lane>>4)*8+j+32ks.
// B (x / h): col = lane&15 (edge), same kslot layout.
// C: col = lane&15 (edge), ch = 16t + 4*(lane>>4) + reg.
__global__ __launch_bounds__(512, 4)
void rcpe_pipe(const float* __restrict__ source,
               const float* __restrict__ target,
               const int*   __restrict__ edge,
               const float* __restrict__ freqs,
               const float* __restrict__ W1,      // f32, for k=128 rank-1 row
               const ushort* __restrict__ W1T,
               const float* __restrict__ b1,
               const float* __restrict__ gamma,
               const float* __restrict__ beta,
               const ushort* __restrict__ W2T,
               const float* __restrict__ b2,
               float* __restrict__ out,
               int E)
{
    __shared__ __align__(16) ushort wbuf[2][16384];   // ping-pong 2 x 32 KB
    __shared__ __align__(16) float b1_lds[4][128];
    __shared__ __align__(16) float gm_lds[4][128];
    __shared__ __align__(16) float bt_lds[4][128];
    __shared__ __align__(16) float w1r_lds[4][128];
    __shared__ __align__(16) float feat_lds[4][128];
    __shared__ __align__(16) float freq_lds[4][64];

    const int tid  = threadIdx.x;     // 0..511
    const int wv   = tid >> 6;        // 0..7
    const int lane = tid & 63;
    const int e4   = lane & 15;
    const int g    = lane >> 4;       // 0..3
    const int ebase = blockIdx.x * 128;
    const int eg    = ebase + wv * 16 + e4;

    // ---- prologue: issue first stage early, then fill LDS tables ----
    stage_tile(W1T, wbuf[0], wv, lane);   // W1[d=0] -> buf0

    {   // params: 512 elements each, one per thread
        const int dd = tid >> 7, c = tid & 127;
        b1_lds[dd][c]  = b1[tid];
        gm_lds[dd][c]  = gamma[tid];
        bt_lds[dd][c]  = beta[tid];
        w1r_lds[dd][c] = W1[(dd * 129 + 128) * 128 + c];
    }
    if (tid < 256) ((float*)freq_lds)[tid] = freqs[tid];

    if (tid < 128) {
        const int e  = ebase + tid;
        const int ec = (e < E) ? e : (E - 1);
        const int s_i = edge[ec];
        const int t_i = edge[E + ec];
        const float sx = source[s_i * 3 + 0];
        const float sy = source[s_i * 3 + 1];
        const float sh = source[s_i * 3 + 2];
        const float tx = target[t_i * 5 + 0];
        const float ty = target[t_i * 5 + 1];
        const float th = target[t_i * 5 + 2];
        const float ts = target[t_i * 5 + 3];
        const float dx = sx - tx;
        const float dy = sy - ty;
        float a = sh - th + PI_F;
        a = fmodf(a, TWO_PI_F);
        if (a < 0.0f) a += TWO_PI_F;
        const float dh  = a - PI_F;
        const float ang = atan2f(dy, dx);
        const float tvx = ts * cosf(th);
        const float tvy = ts * sinf(th);
        const float closing = tvx * cosf(ang) + tvy * sinf(ang);
        feat_lds[0][tid] = dx;
        feat_lds[1][tid] = dy;
        feat_lds[2][tid] = dh;
        feat_lds[3][tid] = closing;
    }

    // ---- y init: sum_d b2 (C layout: ch = 16t + 4g + r) ----
    float4v y[8];
    #pragma unroll
    for (int t = 0; t < 8; ++t) {
        float4v a = {0.f, 0.f, 0.f, 0.f};
        #pragma unroll
        for (int d = 0; d < 4; ++d) {
            const float4v bv = *(const float4v*)(b2 + d * 128 + 16 * t + 4 * g);
            #pragma unroll
            for (int r = 0; r < 4; ++r) a[r] += bv[r];
        }
        y[t] = a;
    }

    __syncthreads();   // buf0 staged; tables ready

    #pragma unroll 1
    for (int d = 0; d < 4; ++d) {
        // ================= phase A: stage W2[d]->buf1 ; trig + GEMM1 from buf0 =====
        stage_tile(W2T + d * 16384, wbuf[1], wv, lane);

        const float fe = feat_lds[d][wv * 16 + e4];

        Frag xf[4];   // ks0=cos lo, ks1=cos hi, ks2=sin lo, ks3=sin hi
        {
            float cl[8], sl[8], ch8[8], sh8[8];
            #pragma unroll
            for (int j = 0; j < 8; ++j) {
                const float frL = freq_lds[d][8 * g + j];
                const float frH = freq_lds[d][32 + 8 * g + j];
                const float tL = __builtin_amdgcn_fractf(fe * frL);
                const float tH = __builtin_amdgcn_fractf(fe * frH);
                sl[j]  = __builtin_amdgcn_sinf(tL);
                cl[j]  = __builtin_amdgcn_cosf(tL);
                sh8[j] = __builtin_amdgcn_sinf(tH);
                ch8[j] = __builtin_amdgcn_cosf(tH);
            }
            #pragma unroll
            for (int p = 0; p < 4; ++p) {
                xf[0].u[p] = pack2(cl[2 * p],  cl[2 * p + 1]);
                xf[1].u[p] = pack2(ch8[2 * p], ch8[2 * p + 1]);
                xf[2].u[p] = pack2(sl[2 * p],  sl[2 * p + 1]);
                xf[3].u[p] = pack2(sh8[2 * p], sh8[2 * p + 1]);
            }
        }

        float4v hacc[8];
        #pragma unroll
        for (int t = 0; t < 8; ++t) {
            float4v acc = *(const float4v*)&b1_lds[d][16 * t + 4 * g];
            #pragma unroll
            for (int ks = 0; ks < 4; ++ks) {
                const short8 aw = *(const short8*)&wbuf[0][(t * 4 + ks) * 512 + lane * 8];
                acc = __builtin_amdgcn_mfma_f32_16x16x32_bf16(aw, xf[ks].s, acc, 0, 0, 0);
            }
            hacc[t] = acc;
        }

        // rank-1: k=128 raw-feature column, exact f32
        #pragma unroll
        for (int t = 0; t < 8; ++t) {
            const float4v wv4 = *(const float4v*)&w1r_lds[d][16 * t + 4 * g];
            #pragma unroll
            for (int r = 0; r < 4; ++r)
                hacc[t][r] = fmaf(fe, wv4[r], hacc[t][r]);
        }

        __syncthreads();   // buf1 (W2[d]) staged; buf0 free to overwrite

        // ============== phase B: stage W1[d+1]->buf0 ; LN + pack + GEMM2 from buf1 ==
        if (d < 3) stage_tile(W1T + (d + 1) * 16384, wbuf[0], wv, lane);

        // LayerNorm + ReLU (reduce over g-lanes: xor 16, 32)
        float sm = 0.f, sq = 0.f;
        #pragma unroll
        for (int t = 0; t < 8; ++t) {
            #pragma unroll
            for (int r = 0; r < 4; ++r) {
                const float v = hacc[t][r];
                sm += v;
                sq = fmaf(v, v, sq);
            }
        }
        sm += __shfl_xor(sm, 16, 64);
        sq += __shfl_xor(sq, 16, 64);
        sm += __shfl_xor(sm, 32, 64);
        sq += __shfl_xor(sq, 32, 64);
        const float mu   = sm * (1.f / 128.f);
        const float var  = sq * (1.f / 128.f) - mu * mu;
        const float rinv = rsqrtf(var + 1e-5f);
        #pragma unroll
        for (int t = 0; t < 8; ++t) {
            const float4v gv = *(const float4v*)&gm_lds[d][16 * t + 4 * g];
            const float4v bv = *(const float4v*)&bt_lds[d][16 * t + 4 * g];
            #pragma unroll
            for (int r = 0; r < 4; ++r) {
                float v = (hacc[t][r] - mu) * rinv;
                v = fmaf(v, gv[r], bv[r]);
                hacc[t][r] = fmaxf(v, 0.f);
            }
        }

        // zero-shuffle B-frags: pi-permuted k makes everything lane-local
        Frag bfr[4];
        #pragma unroll
        for (int ks = 0; ks < 4; ++ks) {
            bfr[ks].u[0] = pack2(hacc[2 * ks][0],     hacc[2 * ks][1]);
            bfr[ks].u[1] = pack2(hacc[2 * ks][2],     hacc[2 * ks][3]);
            bfr[ks].u[2] = pack2(hacc[2 * ks + 1][0], hacc[2 * ks + 1][1]);
            bfr[ks].u[3] = pack2(hacc[2 * ks + 1][2], hacc[2 * ks + 1][3]);
        }

        // GEMM2: y += W2^T h^T
        #pragma unroll
        for (int t = 0; t < 8; ++t) {
            float4v acc = y[t];
            #pragma unroll
            for (int ks = 0; ks < 4; ++ks) {
                const short8 aw = *(const short8*)&wbuf[1][(t * 4 + ks) * 512 + lane * 8];
                acc = __builtin_amdgcn_mfma_f32_16x16x32_bf16(aw, bfr[ks].s, acc, 0, 0, 0);
            }
            y[t] = acc;
        }

        __syncthreads();   // buf0 (W1[d+1]) staged; buf1 free for next d
    }

    // ---- store: 4 g-lanes per edge form full 64B sectors ----
    if (eg < E) {
        #pragma unroll
        for (int t = 0; t < 8; ++t) {
            *(float4v*)(out + eg * 128 + 16 * t + 4 * g) = y[t];
        }
    }
}

} // namespace

extern "C" void kernel_launch(void* const* d_in, const int* in_sizes, int n_in,
                              void* d_out, int out_size, void* d_ws, size_t ws_size,
                              hipStream_t stream) {
    const float* source = (const float*)d_in[0];
    const float* target = (const float*)d_in[1];
    const int*   edge   = (const int*)  d_in[2];
    const float* freqs  = (const float*)d_in[3];
    const float* W1     = (const float*)d_in[4];
    const float* b1     = (const float*)d_in[5];
    const float* gammap = (const float*)d_in[6];
    const float* betap  = (const float*)d_in[7];
    const float* W2     = (const float*)d_in[8];
    const float* b2     = (const float*)d_in[9];
    float* out = (float*)d_out;

    ushort* W1T = (ushort*)d_ws;                       // 131072 B
    ushort* W2T = (ushort*)((char*)d_ws + 131072);     // 131072 B

    const int E = in_sizes[2] / 2;      // edge is (2, E); E = 200000

    prep_weights<<<dim3(512), dim3(256), 0, stream>>>(W1, W2, W1T, W2T);

    const int nblocks = (E + 127) / 128;   // 1563 (tail block: 64 edges)
    rcpe_pipe<<<dim3(nblocks), dim3(512), 0, stream>>>(
        source, target, edge, freqs, W1, W1T, b1, gammap, betap, W2T, b2, out, E);
}